// Round 1
// baseline (380.279 us; speedup 1.0000x reference)
//
#include <hip/hip_runtime.h>
#include <math.h>

// Problem constants (KimiLinearKDADecode): HK=HV=32, D=128, K=4, B=128
#define NHK   32
#define NHV   32
#define DDIM  128
#define NB    128
#define QKVC  12288   // (2*HK+HV)*D

__device__ __forceinline__ float sigmoid_f(float x) { return 1.0f / (1.0f + expf(-x)); }
__device__ __forceinline__ float silu_f(float x)    { return x * sigmoid_f(x); }
__device__ __forceinline__ float softplus_f(float x){ return (x > 20.0f) ? x : log1pf(expf(x)); }

// One block per (b, h). 256 threads.
//  o[b,h,v] = sum_k qn[k]*eg[k]*S0[k,v]
//           + (qn.kn) * (v[v] - sum_k kn[k]*eg[k]*S0[k,v]) * sigmoid(beta)
__global__ __launch_bounds__(256)
void kda_decode_kernel(const float* __restrict__ mixed,    // (B, 12288)
                       const float* __restrict__ fgate,    // (B, 4096)
                       const float* __restrict__ beta,     // (B, 32)
                       const float* __restrict__ cstate,   // (B, 12288, 3)
                       const float* __restrict__ cweight,  // (12288, 4)
                       const float* __restrict__ ssm,      // (B, 32, 128, 128)
                       const float* __restrict__ A_log,    // (32,)
                       const float* __restrict__ dt_bias,  // (4096,)
                       float* __restrict__ out)            // (B, 32, 128)
{
    const int bh  = blockIdx.x;
    const int b   = bh >> 5;
    const int h   = bh & 31;
    const int tid = threadIdx.x;

    __shared__ float red[3][256];
    __shared__ float w_q[DDIM];     // qn[k]*eg[k]
    __shared__ float w_k[DDIM];     // kn[k]*eg[k]
    __shared__ float v_s[DDIM];     // v row (post conv+silu)
    __shared__ float pq[8][DDIM];   // partial column sums (q-weighted)
    __shared__ float pk[8][DDIM];   // partial column sums (k-weighted)

    // ---- prologue: fused causal-conv + SiLU for this head's q/k/v channels ----
    float xq = 0.f, xk = 0.f, xv = 0.f;
    if (tid < DDIM) {
        const int d  = tid;
        const int cq = h * DDIM + d;
        const int ck = (NHK + h) * DDIM + d;
        const int cv = (2 * NHK + h) * DDIM + d;
        const size_t boff3 = (size_t)b * QKVC * 3;
        const size_t boff1 = (size_t)b * QKVC;

        {
            const float* s = cstate + boff3 + (size_t)cq * 3;
            const float* w = cweight + (size_t)cq * 4;
            xq = silu_f(s[0]*w[0] + s[1]*w[1] + s[2]*w[2] + mixed[boff1 + cq]*w[3]);
        }
        {
            const float* s = cstate + boff3 + (size_t)ck * 3;
            const float* w = cweight + (size_t)ck * 4;
            xk = silu_f(s[0]*w[0] + s[1]*w[1] + s[2]*w[2] + mixed[boff1 + ck]*w[3]);
        }
        {
            const float* s = cstate + boff3 + (size_t)cv * 3;
            const float* w = cweight + (size_t)cv * 4;
            xv = silu_f(s[0]*w[0] + s[1]*w[1] + s[2]*w[2] + mixed[boff1 + cv]*w[3]);
        }
    }

    // ---- block reductions: |q|^2, |k|^2, q.k ----
    red[0][tid] = (tid < DDIM) ? xq * xq : 0.f;
    red[1][tid] = (tid < DDIM) ? xk * xk : 0.f;
    red[2][tid] = (tid < DDIM) ? xq * xk : 0.f;
    __syncthreads();
    for (int s = 128; s > 0; s >>= 1) {
        if (tid < s) {
            red[0][tid] += red[0][tid + s];
            red[1][tid] += red[1][tid + s];
            red[2][tid] += red[2][tid + s];
        }
        __syncthreads();
    }
    const float q2  = red[0][0];
    const float k2  = red[1][0];
    const float qkd = red[2][0];

    const float dscale = 0.08838834764831845f;   // 1/sqrt(128)
    const float rq = rsqrtf(q2 + 1e-6f);
    const float rk = rsqrtf(k2 + 1e-6f);
    const float qk = qkd * rq * rk * dscale;     // qn . kn
    const float bsig = sigmoid_f(beta[b * NHV + h]);

    if (tid < DDIM) {
        const int d = tid;
        const float g  = -expf(A_log[h]) *
                         softplus_f(fgate[(size_t)b * (NHV * DDIM) + h * DDIM + d] +
                                    dt_bias[h * DDIM + d]);
        const float eg = expf(g);
        w_q[d] = xq * rq * dscale * eg;
        w_k[d] = xk * rk * eg;
        v_s[d] = xv;
    }
    __syncthreads();

    // ---- main pass: stream S0[b,h] (128x128 f32) once, two weighted column sums ----
    const float* Sb = ssm + (size_t)(b * NHV + h) * DDIM * DDIM;
    const int g8 = tid >> 5;          // k-group 0..7 (16 rows each)
    const int v4 = (tid & 31) * 4;    // 4 consecutive columns per lane

    float4 accq = {0.f, 0.f, 0.f, 0.f};
    float4 acck = {0.f, 0.f, 0.f, 0.f};
    #pragma unroll
    for (int kk = 0; kk < 16; ++kk) {
        const int k = g8 * 16 + kk;
        const float4 s = *reinterpret_cast<const float4*>(Sb + (size_t)k * DDIM + v4);
        const float wq = w_q[k];
        const float wk = w_k[k];
        accq.x = fmaf(wq, s.x, accq.x); accq.y = fmaf(wq, s.y, accq.y);
        accq.z = fmaf(wq, s.z, accq.z); accq.w = fmaf(wq, s.w, accq.w);
        acck.x = fmaf(wk, s.x, acck.x); acck.y = fmaf(wk, s.y, acck.y);
        acck.z = fmaf(wk, s.z, acck.z); acck.w = fmaf(wk, s.w, acck.w);
    }
    pq[g8][v4 + 0] = accq.x; pq[g8][v4 + 1] = accq.y;
    pq[g8][v4 + 2] = accq.z; pq[g8][v4 + 3] = accq.w;
    pk[g8][v4 + 0] = acck.x; pk[g8][v4 + 1] = acck.y;
    pk[g8][v4 + 2] = acck.z; pk[g8][v4 + 3] = acck.w;
    __syncthreads();

    // ---- epilogue: combine partials, apply delta-rule correction, store ----
    if (tid < DDIM) {
        float aq = 0.f, ak = 0.f;
        #pragma unroll
        for (int g = 0; g < 8; ++g) { aq += pq[g][tid]; ak += pk[g][tid]; }
        const float o = aq + qk * (v_s[tid] - ak) * bsig;
        out[(size_t)(b * NHV + h) * DDIM + tid] = o;
    }
}

extern "C" void kernel_launch(void* const* d_in, const int* in_sizes, int n_in,
                              void* d_out, int out_size, void* d_ws, size_t ws_size,
                              hipStream_t stream) {
    const float* mixed   = (const float*)d_in[0];
    const float* fgate   = (const float*)d_in[1];
    const float* beta    = (const float*)d_in[2];
    const float* cstate  = (const float*)d_in[3];
    const float* cweight = (const float*)d_in[4];
    const float* ssm     = (const float*)d_in[5];
    const float* A_log   = (const float*)d_in[6];
    const float* dt_bias = (const float*)d_in[7];
    float* out = (float*)d_out;

    kda_decode_kernel<<<NB * NHV, 256, 0, stream>>>(
        mixed, fgate, beta, cstate, cweight, ssm, A_log, dt_bias, out);
}